// Round 9
// baseline (5508.060 us; speedup 1.0000x reference)
//
#include <hip/hip_runtime.h>
#include <hip/hip_bf16.h>

#define H 8
#define DH 64
#define DMODEL 512
#define SEQ 408
#define BATCH 16
#define NLAYER 10
#define FFDIM 2048
#define CHUNK 68
#define NCHUNK 6
#define M (BATCH*SEQ)   // 6528
#define EPS 1e-5f

typedef __hip_bfloat16 bf16;
typedef unsigned short ushort_t;
typedef short bf8v __attribute__((ext_vector_type(8)));   // 8 bf16 bit-patterns
typedef float f4v  __attribute__((ext_vector_type(4)));

// ---- wsp (pre-split weight scratch) offsets in USHORTS; single source of truth ----
static constexpr size_t QKVG_STRIDE = 2u*512*512;          // 524288 per weight (hi+lo)
static constexpr size_t QKVG_HL     = 512*512;             // 262144 hi->lo offset
static constexpr size_t WO_HI = 0;
static constexpr size_t WO_LO = WO_HI + 512*512;           // 262144
static constexpr size_t W1_HI = WO_LO + 512*512;           // 524288
static constexpr size_t W1_LO = W1_HI + 2048*512;          // 1572864
static constexpr size_t W2_HI = W1_LO + 2048*512;          // 2621440
static constexpr size_t W2_LO = W2_HI + 512*2048;          // 3670016
// end = W2_LO + 512*2048 = 4718592 ushorts = 9.44 MB < rf's 13.37 MB

__device__ __forceinline__ float us2f(unsigned short u){ return __uint_as_float(((unsigned)u) << 16); }
__device__ __forceinline__ unsigned short f2bfs(float f){   // RNE fp32->bf16 bits
  __bf16 h = (__bf16)f;
  return *(unsigned short*)&h;
}
// split fp32 into hi+lo bf16 (combined ~16 mantissa bits)
__device__ __forceinline__ void split2(float f, unsigned short& hi, unsigned short& lo){
  hi = f2bfs(f);
  lo = f2bfs(f - us2f(hi));
}

// async 16-B global -> LDS copy. LDS dest = wave-uniform base + lane*16 (m104);
// staging dests are linear in tid, satisfying this per-wave.
typedef const __attribute__((address_space(1))) unsigned int* gas_ptr;
typedef __attribute__((address_space(3))) unsigned int* las_ptr;
__device__ __forceinline__ void gld16(const void* g, void* l){
  __builtin_amdgcn_global_load_lds((gas_ptr)g, (las_ptr)l, 16, 0, 0);
}

// XCD-aware bijective block swizzle (T1, m204). Requires nwg % 8 == 0
// (grids here: 816 and 1632). bn fastest within an XCD's contiguous range ->
// each XCD's L2 holds the full B weight slice (1-4.2 MB, L2-resident).
__device__ __forceinline__ int xcd_swz(int fid, int nwg){
  int q = nwg >> 3;
  return (fid & 7) * q + (fid >> 3);
}

__global__ void embed_kernel(const int* __restrict__ tokens, const float* __restrict__ emb,
                             float* __restrict__ x){
  int idx = blockIdx.x*256 + threadIdx.x;
  if (idx >= M*DMODEL) return;
  int r = idx >> 9; int d = idx & 511;
  x[idx] = emb[(size_t)tokens[r]*DMODEL + d];
}

// x fp32 -> (h_hi, h_lo) bf16 pair
__global__ __launch_bounds__(256) void ln_kernel(const float* __restrict__ x,
    const float* __restrict__ w, const float* __restrict__ b,
    ushort_t* __restrict__ hhi, ushort_t* __restrict__ hlo){
  __shared__ float red[8];
  int r = blockIdx.x, tid = threadIdx.x;
  size_t base = (size_t)r*DMODEL;
  float v0 = x[base + tid], v1 = x[base + tid + 256];
  float s = v0 + v1, s2 = v0*v0 + v1*v1;
  int lane = tid & 63, wv = tid >> 6;
  #pragma unroll
  for (int o = 32; o; o >>= 1){ s += __shfl_xor(s, o); s2 += __shfl_xor(s2, o); }
  if (lane == 0){ red[wv] = s; red[wv+4] = s2; }
  __syncthreads();
  float tot  = red[0]+red[1]+red[2]+red[3];
  float tot2 = red[4]+red[5]+red[6]+red[7];
  float mean = tot * (1.0f/512.0f);
  float var  = tot2 * (1.0f/512.0f) - mean*mean;
  float rinv = rsqrtf(var + EPS);
  float o0 = (v0-mean)*rinv*w[tid]     + b[tid];
  float o1 = (v1-mean)*rinv*w[tid+256] + b[tid+256];
  unsigned short hi, lo;
  split2(o0, hi, lo); hhi[base+tid] = hi; hlo[base+tid] = lo;
  split2(o1, hi, lo); hhi[base+tid+256] = hi; hlo[base+tid+256] = lo;
}

// ---------------- weight pre-split: W[K][N] fp32 -> transposed [N][K] bf16 hi/lo ----------------
__device__ __forceinline__ void wsplit_tile(const float* __restrict__ W,
    ushort_t* __restrict__ hi, ushort_t* __restrict__ lo,
    int N, int K, int n0, int k0)
{
  __shared__ float tb[32][33];
  int tx = threadIdx.x & 31, ty = threadIdx.x >> 5;   // 256 thr = 32x8
  #pragma unroll
  for (int r = 0; r < 32; r += 8)
    tb[ty+r][tx] = W[(size_t)(k0+ty+r)*N + n0 + tx];
  __syncthreads();
  #pragma unroll
  for (int r = 0; r < 32; r += 8){
    float v = tb[tx][ty+r];                 // = W[(k0+tx)*N + n0+ty+r]
    unsigned short h, l; split2(v, h, l);
    size_t o = (size_t)(n0+ty+r)*K + k0 + tx;
    hi[o] = h; lo[o] = l;
  }
}

// qkvg pairs: wsp layout [4][hi(262144)][lo(262144)] ushorts (4 MB total)
__global__ __launch_bounds__(256) void wsplit_qkvg_kernel(
    const float* __restrict__ Wq, const float* __restrict__ Wk,
    const float* __restrict__ Wv, const float* __restrict__ Wg,
    ushort_t* __restrict__ wsp)
{
  int z = blockIdx.z;
  const float* W = (z==0)?Wq:(z==1)?Wk:(z==2)?Wv:Wg;
  ushort_t* hi = wsp + (size_t)z*QKVG_STRIDE;
  wsplit_tile(W, hi, hi + QKVG_HL, 512, 512, blockIdx.x*32, blockIdx.y*32);
}

// Wo+w1+w2 pairs after gnorm consumes rf (offsets per constants above)
__global__ __launch_bounds__(256) void wsplit_ffo_kernel(
    const float* __restrict__ Wo, const float* __restrict__ w1,
    const float* __restrict__ w2, ushort_t* __restrict__ wsp)
{
  int b = blockIdx.x;
  const float* W; ushort_t* hi; int N, K, n0, k0;
  if (b < 256){                     // Wo: 512x512 -> [512][512]
    W = Wo; hi = wsp + WO_HI; N = 512; K = 512;
    n0 = (b & 15)*32; k0 = (b >> 4)*32;
  } else if (b < 1280){             // w1: [512][2048] -> [2048][512]
    int bb = b - 256;
    W = w1; hi = wsp + W1_HI; N = 2048; K = 512;
    n0 = (bb & 63)*32; k0 = (bb >> 6)*32;
  } else {                          // w2: [2048][512] -> [512][2048]
    int bb = b - 1280;
    W = w2; hi = wsp + W2_HI; N = 512; K = 2048;
    n0 = (bb & 15)*32; k0 = (bb >> 4)*32;
  }
  wsplit_tile(W, hi, hi + (size_t)N*K, N, K, n0, k0);
}

// ---------------- split-precision MFMA GEMM, 64xTBN tile, B-direct-from-L2 ----
// bf16 hi/lo pair, 3 MFMAs: hi*lo + lo*hi + hi*hi (bit-identical order).
// A: staged via global_load_lds into 3 x 8 KB LDS buffers (A-only, 24 KB total).
//    One barrier per K-step; uniform vmcnt(2) before it (stage t landed, stage
//    t+1 in flight across barrier = T4). Stage t+2 issued post-barrier into the
//    buffer last read at t-1 (its reads completed pre-barrier) -> race-free.
// B: NOT staged. Frags loaded per-lane from the pre-split [N][K] weights
//    (global_load_dwordx4; B slice is XCD-L2-resident under the bn-fastest
//    swizzle; wm-pair waves re-hit L1). Compiler manages B waits.
// Round-8 lesson: ds_read_b128 "bank conflicts" are intrinsic (+4cy each,
// layout-invariant) — linear LDS, no swizzle.
#define BK 32

template<int TBN>
__global__ __launch_bounds__(256) void gemm_ps_kernel(
    const ushort_t* __restrict__ Ahi, const ushort_t* __restrict__ Alo,
    const ushort_t* __restrict__ Bhi, const ushort_t* __restrict__ Blo,
    const float* __restrict__ bias,
    const float* Cin, float* Cout, ushort_t* Co_hi, ushort_t* Co_lo,
    int N, int K, int epi)
{
  constexpr int TNW = TBN/32;   // 16-col n-tiles per wave
  __shared__ __align__(16) short AsH[3][64*BK];   // 4 KB per buffer per plane
  __shared__ __align__(16) short AsL[3][64*BK];
  int tid = threadIdx.x;
  int lane = tid & 63, wave = tid >> 6;
  int wm = (wave >> 1) * 32, wn = (wave & 1) * (TBN/2);
  int l15 = lane & 15, quad = lane >> 4;

  int nwg = gridDim.x * gridDim.y;
  int fid = blockIdx.y * gridDim.x + blockIdx.x;
  int swz = xcd_swz(fid, nwg);
  int bn = (swz % gridDim.x) * TBN;
  int bm = (swz / gridDim.x) * 64;

  f4v acc[2][TNW];
  #pragma unroll
  for (int i = 0; i < 2; i++)
    #pragma unroll
    for (int j = 0; j < TNW; j++) acc[i][j] = (f4v){0.f,0.f,0.f,0.f};

  // A staging map: 64 rows x 32 k-shorts, 4 threads/row, dest = tid*16 B linear
  int arow = tid >> 2, ak = (tid & 3) * 8;
  const ushort_t* aHp = Ahi + (size_t)(bm + arow)*K + ak;
  const ushort_t* aLp = Alo + (size_t)(bm + arow)*K + ak;
  // B frag row pointers (per-lane): row = bn + wn + j*16 + l15, chunk quad*8
  const ushort_t* bHp[TNW];
  const ushort_t* bLp[TNW];
  #pragma unroll
  for (int j = 0; j < TNW; j++){
    size_t ro = (size_t)(bn + wn + j*16 + l15)*K + quad*8;
    bHp[j] = Bhi + ro;
    bLp[j] = Blo + ro;
  }

  auto STAGE = [&](int buf, int kofs){
    gld16(aHp + kofs, &AsH[buf][tid*8]);
    gld16(aLp + kofs, &AsL[buf][tid*8]);
  };

  STAGE(0, 0);
  STAGE(1, BK);
  const int nt = K / BK;
  for (int t = 0; t < nt; t++){
    // outstanding A stages (B loads of t-1 already consumed/drained): {t, t+1}.
    // vmcnt(2) -> stage t landed, stage t+1 stays in flight across the barrier.
    asm volatile("s_waitcnt vmcnt(2)" ::: "memory");
    __builtin_amdgcn_s_barrier();
    asm volatile("" ::: "memory");
    if (t + 2 < nt) STAGE((t + 2) % 3, (t + 2)*BK);   // buf last read at t-1: safe
    int cur = t % 3;
    bf8v bfh[TNW], bfl[TNW];
    #pragma unroll
    for (int j = 0; j < TNW; j++){
      bfh[j] = *(const bf8v*)(bHp[j] + t*BK);
      bfl[j] = *(const bf8v*)(bLp[j] + t*BK);
    }
    bf8v afh[2], afl[2];
    #pragma unroll
    for (int i = 0; i < 2; i++){
      afh[i] = *(const bf8v*)&AsH[cur][(wm + i*16 + l15)*BK + quad*8];
      afl[i] = *(const bf8v*)&AsL[cur][(wm + i*16 + l15)*BK + quad*8];
    }
    #pragma unroll
    for (int i = 0; i < 2; i++)
      #pragma unroll
      for (int j = 0; j < TNW; j++){
        acc[i][j] = __builtin_amdgcn_mfma_f32_16x16x32_bf16(afh[i], bfl[j], acc[i][j], 0, 0, 0);
        acc[i][j] = __builtin_amdgcn_mfma_f32_16x16x32_bf16(afl[i], bfh[j], acc[i][j], 0, 0, 0);
        acc[i][j] = __builtin_amdgcn_mfma_f32_16x16x32_bf16(afh[i], bfh[j], acc[i][j], 0, 0, 0);
      }
  }
  // epilogue: C/D layout col = lane&15, row = quad*4 + reg  [m89/m91 verified]
  #pragma unroll
  for (int i = 0; i < 2; i++){
    int m0 = bm + wm + i*16 + quad*4;
    #pragma unroll
    for (int j = 0; j < TNW; j++){
      int n = bn + wn + j*16 + l15;
      float bsv = bias[n];
      #pragma unroll
      for (int r = 0; r < 4; r++){
        int m = m0 + r;
        float c = acc[i][j][r] + bsv;
        if (epi == 1) c = c / (1.0f + expf(-c));
        if (epi == 2) c += Cin[(size_t)m*N + n];
        if (Co_hi){
          unsigned short hi, lo; split2(c, hi, lo);
          Co_hi[(size_t)m*N + n] = hi;
          Co_lo[(size_t)m*N + n] = lo;
        } else {
          Cout[(size_t)m*N + n] = c;
        }
      }
    }
  }
}

// ---------------- fused Q/K/V/G GEMM: 4 pre-split weights, one dispatch ----------------
// grid (16, M/64) = 1632 blocks: (swizzled x)>>2 selects weight, (x&3)*128 is bn.
// Same A-only 3-buffer pipeline; B-direct from L2; TBN=128 geometry.
__global__ __launch_bounds__(256) void gemm_qkvg_kernel(
    const ushort_t* __restrict__ Ahi, const ushort_t* __restrict__ Alo,
    const ushort_t* __restrict__ wsp,
    const float* __restrict__ bq, const float* __restrict__ bk,
    const float* __restrict__ bv, const float* __restrict__ bg,
    float* __restrict__ qo, float* __restrict__ ko,
    float* __restrict__ vo, float* __restrict__ go)
{
  const int N = DMODEL, K = DMODEL;
  __shared__ __align__(16) short AsH[3][64*BK];
  __shared__ __align__(16) short AsL[3][64*BK];
  int tid = threadIdx.x;
  int lane = tid & 63, wave = tid >> 6;
  int wm = (wave >> 1) * 32, wn = (wave & 1) * 64;
  int l15 = lane & 15, quad = lane >> 4;

  int nwg = gridDim.x * gridDim.y;          // 1632
  int fid = blockIdx.y * gridDim.x + blockIdx.x;
  int swz = xcd_swz(fid, nwg);
  int bx = swz % gridDim.x;
  int which = bx >> 2;
  int bn = (bx & 3) * 128;
  int bm = (swz / gridDim.x) * 64;

  const ushort_t* Bhi = wsp + (size_t)which * QKVG_STRIDE;
  const ushort_t* Blo = Bhi + QKVG_HL;
  const float* bias = (which==0) ? bq : (which==1) ? bk : (which==2) ? bv : bg;
  float* out        = (which==0) ? qo : (which==1) ? ko : (which==2) ? vo : go;

  f4v acc[2][4];
  #pragma unroll
  for (int i = 0; i < 2; i++)
    #pragma unroll
    for (int j = 0; j < 4; j++) acc[i][j] = (f4v){0.f,0.f,0.f,0.f};

  int arow = tid >> 2, ak = (tid & 3) * 8;
  const ushort_t* aHp = Ahi + (size_t)(bm + arow)*K + ak;
  const ushort_t* aLp = Alo + (size_t)(bm + arow)*K + ak;
  const ushort_t* bHp[4];
  const ushort_t* bLp[4];
  #pragma unroll
  for (int j = 0; j < 4; j++){
    size_t ro = (size_t)(bn + wn + j*16 + l15)*K + quad*8;
    bHp[j] = Bhi + ro;
    bLp[j] = Blo + ro;
  }

  auto STAGE = [&](int buf, int kofs){
    gld16(aHp + kofs, &AsH[buf][tid*8]);
    gld16(aLp + kofs, &AsL[buf][tid*8]);
  };

  STAGE(0, 0);
  STAGE(1, BK);
  const int nt = K / BK;   // 16
  for (int t = 0; t < nt; t++){
    asm volatile("s_waitcnt vmcnt(2)" ::: "memory");
    __builtin_amdgcn_s_barrier();
    asm volatile("" ::: "memory");
    if (t + 2 < nt) STAGE((t + 2) % 3, (t + 2)*BK);
    int cur = t % 3;
    bf8v bfh[4], bfl[4];
    #pragma unroll
    for (int j = 0; j < 4; j++){
      bfh[j] = *(const bf8v*)(bHp[j] + t*BK);
      bfl[j] = *(const bf8v*)(bLp[j] + t*BK);
    }
    bf8v afh[2], afl[2];
    #pragma unroll
    for (int i = 0; i < 2; i++){
      afh[i] = *(const bf8v*)&AsH[cur][(wm + i*16 + l15)*BK + quad*8];
      afl[i] = *(const bf8v*)&AsL[cur][(wm + i*16 + l15)*BK + quad*8];
    }
    #pragma unroll
    for (int i = 0; i < 2; i++)
      #pragma unroll
      for (int j = 0; j < 4; j++){
        acc[i][j] = __builtin_amdgcn_mfma_f32_16x16x32_bf16(afh[i], bfl[j], acc[i][j], 0, 0, 0);
        acc[i][j] = __builtin_amdgcn_mfma_f32_16x16x32_bf16(afl[i], bfh[j], acc[i][j], 0, 0, 0);
        acc[i][j] = __builtin_amdgcn_mfma_f32_16x16x32_bf16(afh[i], bfh[j], acc[i][j], 0, 0, 0);
      }
  }
  #pragma unroll
  for (int i = 0; i < 2; i++){
    int m0 = bm + wm + i*16 + quad*4;
    #pragma unroll
    for (int j = 0; j < 4; j++){
      int n = bn + wn + j*16 + l15;
      float bsv = bias[n];
      #pragma unroll
      for (int r = 0; r < 4; r++){
        int m = m0 + r;
        float c = acc[i][j][r] + bsv;
        if (which == 3) c = c / (1.0f + expf(-c));   // silu on gate
        out[(size_t)m*N + n] = c;
      }
    }
  }
}

__global__ void rope_kernel(float* __restrict__ q, float* __restrict__ k){
  int idx = blockIdx.x*256 + threadIdx.x;
  if (idx >= M*256) return;
  int r = idx >> 8, p = idx & 255;
  int hh = p >> 5, i = p & 31;
  int s = r % SEQ;
  float inv = powf(10000.0f, -(float)(2*i) * (1.0f/64.0f));
  float ang = (float)s * inv;
  float sn, c; sincosf(ang, &sn, &c);
  size_t base = (size_t)r*DMODEL + hh*64 + i;
  float q1 = q[base], q2 = q[base+32];
  q[base]    = q1*c - q2*sn;
  q[base+32] = q2*c + q1*sn;
  float k1 = k[base], k2 = k[base+32];
  const float sc = 0.125f;   // dh^-0.5
  k[base]    = (k1*c - k2*sn)*sc;
  k[base+32] = (k2*c + k1*sn)*sc;
}

// ---------------- retention, 3-phase parallel scan ----------------
__global__ __launch_bounds__(256) void ret_chunkkv_kernel(
    const float* __restrict__ k, const float* __restrict__ v, float* __restrict__ Ast)
{
  __shared__ __align__(16) float kT[DH][CHUNK];
  __shared__ __align__(16) float vs[CHUNK][DH];
  __shared__ float gpw[CHUNK];
  int tid = threadIdx.x;
  int c = blockIdx.x % NCHUNK;
  int bh = blockIdx.x / NCHUNK;
  int hh = bh & 7, b = bh >> 3;
  float gamma = 1.0f - exp2f(-5.0f - (float)hh);
  if (tid < CHUNK) gpw[tid] = powf(gamma, (float)(CHUNK-1-tid));
  size_t rowbase = ((size_t)(b*SEQ + c*CHUNK))*DMODEL + hh*DH;
  for (int e = tid; e < CHUNK*DH; e += 256){
    int i = e >> 6, d = e & 63;
    size_t g = rowbase + (size_t)i*DMODEL + d;
    kT[d][i] = k[g];
    vs[i][d] = v[g];
  }
  __syncthreads();
  float* A = Ast + (size_t)blockIdx.x * (DH*DH);
  for (int e = tid; e < DH*16; e += 256){
    int d = e >> 4, q4 = (e & 15) * 4;
    float4 a4 = {0,0,0,0};
    for (int j = 0; j < CHUNK; j++){
      float kj = kT[d][j] * gpw[j];
      float4 v4 = *(const float4*)&vs[j][q4];
      a4.x += kj*v4.x; a4.y += kj*v4.y; a4.z += kj*v4.z; a4.w += kj*v4.w;
    }
    *(float4*)&A[d*DH + q4] = a4;
  }
}

__global__ __launch_bounds__(256) void ret_scan_kernel(float* __restrict__ Ast)
{
  int bh = blockIdx.x, hh = bh & 7;
  float gamma = 1.0f - exp2f(-5.0f - (float)hh);
  float chdec = powf(gamma, (float)CHUNK);
  int tid = threadIdx.x;
  float4 run[4];
  #pragma unroll
  for (int t = 0; t < 4; t++) run[t] = (float4){0,0,0,0};
  size_t base = (size_t)bh * NCHUNK * (DH*DH) + (size_t)tid*16;
  for (int c = 0; c < NCHUNK; c++){
    float4* slot = (float4*)(Ast + base + (size_t)c*(DH*DH));
    float4 a[4];
    #pragma unroll
    for (int t = 0; t < 4; t++) a[t] = slot[t];
    #pragma unroll
    for (int t = 0; t < 4; t++) slot[t] = run[t];
    #pragma unroll
    for (int t = 0; t < 4; t++){
      run[t].x = run[t].x*chdec + a[t].x;
      run[t].y = run[t].y*chdec + a[t].y;
      run[t].z = run[t].z*chdec + a[t].z;
      run[t].w = run[t].w*chdec + a[t].w;
    }
  }
}

__global__ __launch_bounds__(256) void ret_out_kernel(
    const float* __restrict__ q, const float* __restrict__ k, const float* __restrict__ v,
    const float* __restrict__ Ast, float* __restrict__ ret)
{
  __shared__ __align__(16) float qs[CHUNK][DH];
  __shared__ __align__(16) float kT[DH][CHUNK];
  __shared__ __align__(16) float vs[CHUNK][DH];
  __shared__ __align__(16) float sts[DH*DH];
  __shared__ float inner[34][CHUNK];
  __shared__ float gpw[CHUNK];
  int tid = threadIdx.x;
  int c = blockIdx.x % NCHUNK;
  int bh = blockIdx.x / NCHUNK;
  int hh = bh & 7, b = bh >> 3;
  float gamma = 1.0f - exp2f(-5.0f - (float)hh);
  if (tid < CHUNK) gpw[tid] = powf(gamma, (float)tid);
  size_t rowbase = ((size_t)(b*SEQ + c*CHUNK))*DMODEL + hh*DH;
  for (int e = tid; e < CHUNK*DH; e += 256){
    int i = e >> 6, d = e & 63;
    size_t g = rowbase + (size_t)i*DMODEL + d;
    qs[i][d] = q[g];
    kT[d][i] = k[g];
    vs[i][d] = v[g];
  }
  const float* st = Ast + (size_t)blockIdx.x * (DH*DH);
  for (int e = tid*4; e < DH*DH; e += 1024)
    *(float4*)&sts[e] = *(const float4*)&st[e];
  __syncthreads();
  for (int p = 0; p < 2; p++){
    int i0 = p*34;
    for (int e = tid; e < 34*CHUNK; e += 256){
      int ii = e / CHUNK, j = e - ii*CHUNK;
      int i = i0 + ii;
      float val = 0.0f;
      if (j <= i){
        float dot = 0.0f;
        #pragma unroll 16
        for (int d = 0; d < DH; d++) dot += qs[i][d] * kT[d][j];
        val = dot * gpw[i-j];
      }
      inner[ii][j] = val;
    }
    __syncthreads();
    for (int e = tid; e < 34*16; e += 256){
      int ii = e >> 4, q4 = (e & 15) * 4;
      int i = i0 + ii;
      float4 o4 = {0,0,0,0};
      for (int j = 0; j <= i; j++){
        float w = inner[ii][j];
        float4 v4 = *(const float4*)&vs[j][q4];
        o4.x += w*v4.x; o4.y += w*v4.y; o4.z += w*v4.z; o4.w += w*v4.w;
      }
      float4 c4 = {0,0,0,0};
      #pragma unroll 8
      for (int e2 = 0; e2 < DH; e2++){
        float qv = qs[i][e2];
        float4 s4 = *(const float4*)&sts[e2*DH + q4];
        c4.x += qv*s4.x; c4.y += qv*s4.y; c4.z += qv*s4.z; c4.w += qv*s4.w;
      }
      float cd = gpw[i] * gamma;   // gamma^(i+1)
      size_t ob = rowbase + (size_t)i*DMODEL + q4;
      float4 o; o.x = o4.x + cd*c4.x; o.y = o4.y + cd*c4.y;
      o.z = o4.z + cd*c4.z; o.w = o4.w + cd*c4.w;
      *(float4*)&ret[ob] = o;
    }
    __syncthreads();
  }
}

// groupnorm (fp32 in) -> *gate -> bf16 pair out
__global__ __launch_bounds__(512) void gnorm_gate_kernel(const float* __restrict__ ret,
    const float* __restrict__ g, const float* __restrict__ gnw, const float* __restrict__ gnb,
    ushort_t* __restrict__ ohi, ushort_t* __restrict__ olo)
{
  int r = blockIdx.x, tid = threadIdx.x;   // 8 waves; wave w == head w
  size_t idx = (size_t)r*DMODEL + tid;
  float val = ret[idx];
  float s = val, s2 = val*val;
  #pragma unroll
  for (int o = 32; o; o >>= 1){ s += __shfl_xor(s, o); s2 += __shfl_xor(s2, o); }
  float mean = s * (1.0f/64.0f);
  float var  = s2 * (1.0f/64.0f) - mean*mean;
  float y = (val - mean) * rsqrtf(var + EPS);
  y = y * gnw[tid] + gnb[tid];
  y = y * g[idx];
  unsigned short hi, lo; split2(y, hi, lo);
  ohi[idx] = hi; olo[idx] = lo;
}

__global__ void outwrite_kernel(const float* __restrict__ x, float* __restrict__ out){
  int idx = blockIdx.x*256 + threadIdx.x;
  if (idx < M*DMODEL) out[idx] = x[idx];
}

extern "C" void kernel_launch(void* const* d_in, const int* in_sizes, int n_in,
                              void* d_out, int out_size, void* d_ws, size_t ws_size,
                              hipStream_t stream)
{
  (void)in_sizes; (void)n_in; (void)out_size; (void)ws_size;
  const int*   tokens = (const int*)d_in[0];
  const float* emb  = (const float*)d_in[1];
  const float* Wq = (const float*)d_in[2];  const float* bq = (const float*)d_in[3];
  const float* Wk = (const float*)d_in[4];  const float* bk = (const float*)d_in[5];
  const float* Wv = (const float*)d_in[6];  const float* bv = (const float*)d_in[7];
  const float* Wg = (const float*)d_in[8];  const float* bg = (const float*)d_in[9];
  const float* Wo = (const float*)d_in[10]; const float* bo = (const float*)d_in[11];
  const float* gnw = (const float*)d_in[12]; const float* gnb = (const float*)d_in[13];
  const float* ln1w = (const float*)d_in[14]; const float* ln1b = (const float*)d_in[15];
  const float* ln2w = (const float*)d_in[16]; const float* ln2b = (const float*)d_in[17];
  const float* w1 = (const float*)d_in[18]; const float* b1 = (const float*)d_in[19];
  const float* w2 = (const float*)d_in[20]; const float* b2 = (const float*)d_in[21];

  const size_t MD = (size_t)M*DMODEL;
  float* xf = (float*)d_ws;     // fp32 residual [M,512]
  float* qf = xf + MD;          // fp32 q
  float* kf = qf + MD;          // fp32 k
  float* vf = kf + MD;          // fp32 v
  float* gf = vf + MD;          // fp32 gate (silu'd)
  float* rf = gf + MD;          // fp32 retention out / split-weight scratch
  ushort_t* h_hi = (ushort_t*)(rf + MD);  // bf16 LN-out pair [M,512]
  ushort_t* h_lo = h_hi + MD;
  // A/state buffer [768,4096] fp32 (12.58 MB) time-shares the h pair (13.37 MB)
  float* Ast = (float*)h_hi;
  ushort_t* rg_hi = h_hi;
  ushort_t* rg_lo = h_lo;
  ushort_t* ff_hi = (ushort_t*)qf;
  ushort_t* ff_lo = (ushort_t*)vf;
  ushort_t* wsp = (ushort_t*)rf;
  // total footprint unchanged: 6*MD*4 + 2*MD*2 = 93.6 MB (< proven 95.7 MB)

  embed_kernel<<<(M*DMODEL)/256, 256, 0, stream>>>(tokens, emb, xf);

  dim3 gqkvg(16, M/64);           // fused QKVG: (16,102)=1632 blocks
  dim3 g512(DMODEL/64, M/64);     // N=512 GEMMs, 64x64 tile: (8,102)=816 blocks
  dim3 gff(FFDIM/128, M/64);      // w1: (16,102)=1632 blocks
  dim3 gsplit4(16, 16, 4);        // qkvg weight split
  for (int l = 0; l < NLAYER; l++){
    const size_t wO = (size_t)l*DMODEL*DMODEL;
    const size_t bO = (size_t)l*DMODEL;
    const size_t w1O = (size_t)l*DMODEL*FFDIM;
    const size_t b1O = (size_t)l*FFDIM;
    wsplit_qkvg_kernel<<<gsplit4, 256, 0, stream>>>(Wq + wO, Wk + wO, Wv + wO, Wg + wO, wsp);
    ln_kernel<<<M, 256, 0, stream>>>(xf, ln1w + bO, ln1b + bO, h_hi, h_lo);
    gemm_qkvg_kernel<<<gqkvg, 256, 0, stream>>>(h_hi, h_lo, wsp,
        bq + bO, bk + bO, bv + bO, bg + bO,
        qf, kf, vf, gf);
    rope_kernel<<<M, 256, 0, stream>>>(qf, kf);
    ret_chunkkv_kernel<<<BATCH*H*NCHUNK, 256, 0, stream>>>(kf, vf, Ast);
    ret_scan_kernel<<<BATCH*H, 256, 0, stream>>>(Ast);
    ret_out_kernel<<<BATCH*H*NCHUNK, 256, 0, stream>>>(qf, kf, vf, Ast, rf);
    gnorm_gate_kernel<<<M, 512, 0, stream>>>(rf, gf, gnw + bO, gnb + bO, rg_hi, rg_lo);
    wsplit_ffo_kernel<<<2304, 256, 0, stream>>>(Wo + wO, w1 + w1O, w2 + w1O, wsp);
    gemm_ps_kernel<64><<<g512, 256, 0, stream>>>(rg_hi, rg_lo,
        wsp + WO_HI, wsp + WO_LO, bo + bO, xf, xf, nullptr, nullptr, DMODEL, DMODEL, 2);
    ln_kernel<<<M, 256, 0, stream>>>(xf, ln2w + bO, ln2b + bO, h_hi, h_lo);
    gemm_ps_kernel<128><<<gff, 256, 0, stream>>>(h_hi, h_lo,
        wsp + W1_HI, wsp + W1_LO, b1 + b1O, nullptr, nullptr, ff_hi, ff_lo, FFDIM, DMODEL, 1);
    gemm_ps_kernel<64><<<g512, 256, 0, stream>>>(ff_hi, ff_lo,
        wsp + W2_HI, wsp + W2_LO, b2 + bO, xf, xf, nullptr, nullptr, DMODEL, FFDIM, 2);
  }
  outwrite_kernel<<<(M*DMODEL)/256, 256, 0, stream>>>(xf, (float*)d_out);
}

// Round 10
// 3691.488 us; speedup vs baseline: 1.4921x; 1.4921x over previous
//
#include <hip/hip_runtime.h>
#include <hip/hip_bf16.h>

#define H 8
#define DH 64
#define DMODEL 512
#define SEQ 408
#define BATCH 16
#define NLAYER 10
#define FFDIM 2048
#define CHUNK 68
#define NCHUNK 6
#define M (BATCH*SEQ)   // 6528
#define EPS 1e-5f

typedef __hip_bfloat16 bf16;
typedef unsigned short ushort_t;
typedef short bf8v __attribute__((ext_vector_type(8)));   // 8 bf16 bit-patterns
typedef float f4v  __attribute__((ext_vector_type(4)));

// ---- wsp (pre-split weight scratch) offsets in USHORTS; single source of truth ----
static constexpr size_t QKVG_STRIDE = 2u*512*512;          // 524288 per weight (hi+lo)
static constexpr size_t QKVG_HL     = 512*512;             // 262144 hi->lo offset
static constexpr size_t WO_HI = 0;
static constexpr size_t WO_LO = WO_HI + 512*512;           // 262144
static constexpr size_t W1_HI = WO_LO + 512*512;           // 524288
static constexpr size_t W1_LO = W1_HI + 2048*512;          // 1572864
static constexpr size_t W2_HI = W1_LO + 2048*512;          // 2621440
static constexpr size_t W2_LO = W2_HI + 512*2048;          // 3670016
// end = W2_LO + 512*2048 = 4718592 ushorts = 9.44 MB < rf's 13.37 MB

__device__ __forceinline__ float us2f(unsigned short u){ return __uint_as_float(((unsigned)u) << 16); }
__device__ __forceinline__ unsigned short f2bfs(float f){   // RNE fp32->bf16 bits
  __bf16 h = (__bf16)f;
  return *(unsigned short*)&h;
}
// split fp32 into hi+lo bf16 (combined ~16 mantissa bits)
__device__ __forceinline__ void split2(float f, unsigned short& hi, unsigned short& lo){
  hi = f2bfs(f);
  lo = f2bfs(f - us2f(hi));
}

// async 16-B global -> LDS copy. LDS dest = wave-uniform base + lane*16 (m104);
// staging dests are linear in tid, satisfying this per-wave.
typedef const __attribute__((address_space(1))) unsigned int* gas_ptr;
typedef __attribute__((address_space(3))) unsigned int* las_ptr;
__device__ __forceinline__ void gld16(const void* g, void* l){
  __builtin_amdgcn_global_load_lds((gas_ptr)g, (las_ptr)l, 16, 0, 0);
}

// XCD-aware bijective block swizzle (T1, m204). Requires (gridDim.x*gridDim.y)
// % 8 == 0 (grids here: 816 and 3264; applied per z-slice).
__device__ __forceinline__ int xcd_swz(int fid, int nwg){
  int q = nwg >> 3;
  return (fid & 7) * q + (fid >> 3);
}

__global__ void embed_kernel(const int* __restrict__ tokens, const float* __restrict__ emb,
                             float* __restrict__ x){
  int idx = blockIdx.x*256 + threadIdx.x;
  if (idx >= M*DMODEL) return;
  int r = idx >> 9; int d = idx & 511;
  x[idx] = emb[(size_t)tokens[r]*DMODEL + d];
}

// x fp32 -> (h_hi, h_lo) bf16 pair
__global__ __launch_bounds__(256) void ln_kernel(const float* __restrict__ x,
    const float* __restrict__ w, const float* __restrict__ b,
    ushort_t* __restrict__ hhi, ushort_t* __restrict__ hlo){
  __shared__ float red[8];
  int r = blockIdx.x, tid = threadIdx.x;
  size_t base = (size_t)r*DMODEL;
  float v0 = x[base + tid], v1 = x[base + tid + 256];
  float s = v0 + v1, s2 = v0*v0 + v1*v1;
  int lane = tid & 63, wv = tid >> 6;
  #pragma unroll
  for (int o = 32; o; o >>= 1){ s += __shfl_xor(s, o); s2 += __shfl_xor(s2, o); }
  if (lane == 0){ red[wv] = s; red[wv+4] = s2; }
  __syncthreads();
  float tot  = red[0]+red[1]+red[2]+red[3];
  float tot2 = red[4]+red[5]+red[6]+red[7];
  float mean = tot * (1.0f/512.0f);
  float var  = tot2 * (1.0f/512.0f) - mean*mean;
  float rinv = rsqrtf(var + EPS);
  float o0 = (v0-mean)*rinv*w[tid]     + b[tid];
  float o1 = (v1-mean)*rinv*w[tid+256] + b[tid+256];
  unsigned short hi, lo;
  split2(o0, hi, lo); hhi[base+tid] = hi; hlo[base+tid] = lo;
  split2(o1, hi, lo); hhi[base+tid+256] = hi; hlo[base+tid+256] = lo;
}

// ---------------- weight pre-split: W[K][N] fp32 -> transposed [N][K] bf16 hi/lo ----------------
__device__ __forceinline__ void wsplit_tile(const float* __restrict__ W,
    ushort_t* __restrict__ hi, ushort_t* __restrict__ lo,
    int N, int K, int n0, int k0)
{
  __shared__ float tb[32][33];
  int tx = threadIdx.x & 31, ty = threadIdx.x >> 5;   // 256 thr = 32x8
  #pragma unroll
  for (int r = 0; r < 32; r += 8)
    tb[ty+r][tx] = W[(size_t)(k0+ty+r)*N + n0 + tx];
  __syncthreads();
  #pragma unroll
  for (int r = 0; r < 32; r += 8){
    float v = tb[tx][ty+r];                 // = W[(k0+tx)*N + n0+ty+r]
    unsigned short h, l; split2(v, h, l);
    size_t o = (size_t)(n0+ty+r)*K + k0 + tx;
    hi[o] = h; lo[o] = l;
  }
}

// qkvg pairs: wsp layout [4][hi(262144)][lo(262144)] ushorts (4 MB total)
__global__ __launch_bounds__(256) void wsplit_qkvg_kernel(
    const float* __restrict__ Wq, const float* __restrict__ Wk,
    const float* __restrict__ Wv, const float* __restrict__ Wg,
    ushort_t* __restrict__ wsp)
{
  int z = blockIdx.z;
  const float* W = (z==0)?Wq:(z==1)?Wk:(z==2)?Wv:Wg;
  ushort_t* hi = wsp + (size_t)z*QKVG_STRIDE;
  wsplit_tile(W, hi, hi + QKVG_HL, 512, 512, blockIdx.x*32, blockIdx.y*32);
}

// Wo+w1+w2 pairs after gnorm consumes rf (offsets per constants above)
__global__ __launch_bounds__(256) void wsplit_ffo_kernel(
    const float* __restrict__ Wo, const float* __restrict__ w1,
    const float* __restrict__ w2, ushort_t* __restrict__ wsp)
{
  int b = blockIdx.x;
  const float* W; ushort_t* hi; int N, K, n0, k0;
  if (b < 256){                     // Wo: 512x512 -> [512][512]
    W = Wo; hi = wsp + WO_HI; N = 512; K = 512;
    n0 = (b & 15)*32; k0 = (b >> 4)*32;
  } else if (b < 1280){             // w1: [512][2048] -> [2048][512]
    int bb = b - 256;
    W = w1; hi = wsp + W1_HI; N = 2048; K = 512;
    n0 = (bb & 63)*32; k0 = (bb >> 6)*32;
  } else {                          // w2: [2048][512] -> [512][2048]
    int bb = b - 1280;
    W = w2; hi = wsp + W2_HI; N = 512; K = 2048;
    n0 = (bb & 15)*32; k0 = (bb >> 4)*32;
  }
  wsplit_tile(W, hi, hi + (size_t)N*K, N, K, n0, k0);
}

// ---------------- split-precision MFMA GEMM, 64xTBN tile, counted-vmcnt pipeline ----
// bf16 hi/lo pair, 3 MFMAs: hi*lo + lo*hi + hi*hi (bit-identical accumulation
// order to the round-6 passing kernel). Round-6 structure (best measured):
// 2-deep prefetch, counted s_waitcnt vmcnt(LPS) (never 0 in steady state),
// raw s_barrier pair per step; stage t+2 lands in the buffer freed after
// compute of t. Round-9 lesson: B must be STAGED (L2-residency does not hide
// issue-to-use latency on the MFMA critical path).
// Split-K via blockIdx.z (epi==3): each z-slice computes K/gridDim.z and
// atomicAdds its fp32 partial into Cout (which already holds the residual);
// bias added by the z==0 slice only.
// TBN=64: LPS=4, 32 KB LDS (5 blocks/CU cap).  TBN=128: LPS=6, 48 KB (3/CU).
#define BK 32

template<int TBN>
__global__ __launch_bounds__(256) void gemm_ps_kernel(
    const ushort_t* __restrict__ Ahi, const ushort_t* __restrict__ Alo,
    const ushort_t* __restrict__ Bhi, const ushort_t* __restrict__ Blo,
    const float* __restrict__ bias,
    const float* Cin, float* Cout, ushort_t* Co_hi, ushort_t* Co_lo,
    int N, int K, int epi)
{
  constexpr int TNW = TBN/32;   // 16-col n-tiles per wave
  __shared__ __align__(16) short AsH[2][64*BK];
  __shared__ __align__(16) short AsL[2][64*BK];
  __shared__ __align__(16) short BsH[2][TBN*BK];
  __shared__ __align__(16) short BsL[2][TBN*BK];
  int tid = threadIdx.x;
  int lane = tid & 63, wave = tid >> 6;
  int wm = (wave >> 1) * 32, wn = (wave & 1) * (TBN/2);
  int l15 = lane & 15, quad = lane >> 4;

  int nwg = gridDim.x * gridDim.y;
  int fid = blockIdx.y * gridDim.x + blockIdx.x;
  int swz = xcd_swz(fid, nwg);
  int bn = (swz % gridDim.x) * TBN;
  int bm = (swz / gridDim.x) * 64;
  int Kloc = K / gridDim.z;            // split-K slice (gridDim.z==1 normally)
  int k0 = blockIdx.z * Kloc;

  f4v acc[2][TNW];
  #pragma unroll
  for (int i = 0; i < 2; i++)
    #pragma unroll
    for (int j = 0; j < TNW; j++) acc[i][j] = (f4v){0.f,0.f,0.f,0.f};

  // staging maps: dest = tid*16 B (linear; satisfies gload_lds dest rule)
  int arow = tid >> 2, ak = (tid & 3) * 8;      // 64 rows x 32 k per 4 KB plane
  const ushort_t* aHp  = Ahi + (size_t)(bm + arow)*K + k0 + ak;
  const ushort_t* aLp  = Alo + (size_t)(bm + arow)*K + k0 + ak;
  const ushort_t* bHp  = Bhi + (size_t)(bn + arow)*K + k0 + ak;
  const ushort_t* bLp  = Blo + (size_t)(bn + arow)*K + k0 + ak;
  const ushort_t* bHp2 = Bhi + (size_t)(bn + 64 + arow)*K + k0 + ak;   // TBN=128 only
  const ushort_t* bLp2 = Blo + (size_t)(bn + 64 + arow)*K + k0 + ak;

  auto STAGE = [&](int buf, int kofs){
    gld16(aHp + kofs, &AsH[buf][tid*8]);
    gld16(aLp + kofs, &AsL[buf][tid*8]);
    gld16(bHp + kofs, &BsH[buf][tid*8]);
    gld16(bLp + kofs, &BsL[buf][tid*8]);
    if constexpr (TBN == 128){
      gld16(bHp2 + kofs, &BsH[buf][tid*8 + 2048]);
      gld16(bLp2 + kofs, &BsL[buf][tid*8 + 2048]);
    }
  };

  STAGE(0, 0);
  STAGE(1, BK);
  const int nt = Kloc / BK;
  for (int t = 0; t < nt; t++){
    // entering step t outstanding: {stage t, stage t+1}; vmcnt(LPS) -> t landed,
    // stage t+1 stays in flight across the barrier (T4).
    if (t + 1 < nt){
      if constexpr (TBN == 128) asm volatile("s_waitcnt vmcnt(6)" ::: "memory");
      else                      asm volatile("s_waitcnt vmcnt(4)" ::: "memory");
    } else {
      asm volatile("s_waitcnt vmcnt(0)" ::: "memory");
    }
    __builtin_amdgcn_s_barrier();
    asm volatile("" ::: "memory");
    int cur = t & 1;
    bf8v afh[2], afl[2], bfh[TNW], bfl[TNW];
    #pragma unroll
    for (int i = 0; i < 2; i++){
      afh[i] = *(const bf8v*)&AsH[cur][(wm + i*16 + l15)*BK + quad*8];
      afl[i] = *(const bf8v*)&AsL[cur][(wm + i*16 + l15)*BK + quad*8];
    }
    #pragma unroll
    for (int j = 0; j < TNW; j++){
      bfh[j] = *(const bf8v*)&BsH[cur][(wn + j*16 + l15)*BK + quad*8];
      bfl[j] = *(const bf8v*)&BsL[cur][(wn + j*16 + l15)*BK + quad*8];
    }
    #pragma unroll
    for (int i = 0; i < 2; i++)
      #pragma unroll
      for (int j = 0; j < TNW; j++){
        acc[i][j] = __builtin_amdgcn_mfma_f32_16x16x32_bf16(afh[i], bfl[j], acc[i][j], 0, 0, 0);
        acc[i][j] = __builtin_amdgcn_mfma_f32_16x16x32_bf16(afl[i], bfh[j], acc[i][j], 0, 0, 0);
        acc[i][j] = __builtin_amdgcn_mfma_f32_16x16x32_bf16(afh[i], bfh[j], acc[i][j], 0, 0, 0);
      }
    // all this wave's ds_reads done before signaling buffer free (cross-wave WAR)
    asm volatile("s_waitcnt lgkmcnt(0)" ::: "memory");
    __builtin_amdgcn_s_barrier();
    asm volatile("" ::: "memory");
    if (t + 2 < nt) STAGE(cur, (t+2)*BK);   // refill the buffer just freed
  }
  // epilogue: C/D layout col = lane&15, row = quad*4 + reg  [m89/m91 verified]
  #pragma unroll
  for (int i = 0; i < 2; i++){
    int m0 = bm + wm + i*16 + quad*4;
    #pragma unroll
    for (int j = 0; j < TNW; j++){
      int n = bn + wn + j*16 + l15;
      float bsv = bias[n];
      #pragma unroll
      for (int r = 0; r < 4; r++){
        int m = m0 + r;
        if (epi == 3){
          // split-K partial: Cout already holds the residual; z==0 adds bias
          float c = acc[i][j][r] + (blockIdx.z == 0 ? bsv : 0.0f);
          atomicAdd(&Cout[(size_t)m*N + n], c);
          continue;
        }
        float c = acc[i][j][r] + bsv;
        if (epi == 1) c = c / (1.0f + expf(-c));
        if (epi == 2) c += Cin[(size_t)m*N + n];
        if (Co_hi){
          unsigned short hi, lo; split2(c, hi, lo);
          Co_hi[(size_t)m*N + n] = hi;
          Co_lo[(size_t)m*N + n] = lo;
        } else {
          Cout[(size_t)m*N + n] = c;
        }
      }
    }
  }
}

// ---------------- fused Q/K/V/G GEMM: 4 pre-split weights, one dispatch ----------------
// grid (32, M/64) = 3264 blocks: (swizzled x)>>3 selects weight, (x&7)*64 is bn.
// TBN=64 geometry (32 KB LDS -> 5 blocks/CU cap), round-6 pipeline.
__global__ __launch_bounds__(256) void gemm_qkvg_kernel(
    const ushort_t* __restrict__ Ahi, const ushort_t* __restrict__ Alo,
    const ushort_t* __restrict__ wsp,
    const float* __restrict__ bq, const float* __restrict__ bk,
    const float* __restrict__ bv, const float* __restrict__ bg,
    float* __restrict__ qo, float* __restrict__ ko,
    float* __restrict__ vo, float* __restrict__ go)
{
  const int N = DMODEL, K = DMODEL;
  __shared__ __align__(16) short AsH[2][64*BK];
  __shared__ __align__(16) short AsL[2][64*BK];
  __shared__ __align__(16) short BsH[2][64*BK];
  __shared__ __align__(16) short BsL[2][64*BK];
  int tid = threadIdx.x;
  int lane = tid & 63, wave = tid >> 6;
  int wm = (wave >> 1) * 32, wn = (wave & 1) * 32;
  int l15 = lane & 15, quad = lane >> 4;

  int nwg = gridDim.x * gridDim.y;          // 3264
  int fid = blockIdx.y * gridDim.x + blockIdx.x;
  int swz = xcd_swz(fid, nwg);
  int bx = swz % gridDim.x;                 // 0..31
  int which = bx >> 3;
  int bn = (bx & 7) * 64;
  int bm = (swz / gridDim.x) * 64;

  const ushort_t* Bhi = wsp + (size_t)which * QKVG_STRIDE;
  const ushort_t* Blo = Bhi + QKVG_HL;
  const float* bias = (which==0) ? bq : (which==1) ? bk : (which==2) ? bv : bg;
  float* out        = (which==0) ? qo : (which==1) ? ko : (which==2) ? vo : go;

  f4v acc[2][2];
  #pragma unroll
  for (int i = 0; i < 2; i++)
    #pragma unroll
    for (int j = 0; j < 2; j++) acc[i][j] = (f4v){0.f,0.f,0.f,0.f};

  int arow = tid >> 2, ak = (tid & 3) * 8;
  const ushort_t* aHp = Ahi + (size_t)(bm + arow)*K + ak;
  const ushort_t* aLp = Alo + (size_t)(bm + arow)*K + ak;
  const ushort_t* bHp = Bhi + (size_t)(bn + arow)*K + ak;
  const ushort_t* bLp = Blo + (size_t)(bn + arow)*K + ak;

  auto STAGE = [&](int buf, int kofs){
    gld16(aHp + kofs, &AsH[buf][tid*8]);
    gld16(aLp + kofs, &AsL[buf][tid*8]);
    gld16(bHp + kofs, &BsH[buf][tid*8]);
    gld16(bLp + kofs, &BsL[buf][tid*8]);
  };

  STAGE(0, 0);
  STAGE(1, BK);
  const int nt = K / BK;   // 16
  for (int t = 0; t < nt; t++){
    if (t + 1 < nt) asm volatile("s_waitcnt vmcnt(4)" ::: "memory");
    else            asm volatile("s_waitcnt vmcnt(0)" ::: "memory");
    __builtin_amdgcn_s_barrier();
    asm volatile("" ::: "memory");
    int cur = t & 1;
    bf8v afh[2], afl[2], bfh[2], bfl[2];
    #pragma unroll
    for (int i = 0; i < 2; i++){
      afh[i] = *(const bf8v*)&AsH[cur][(wm + i*16 + l15)*BK + quad*8];
      afl[i] = *(const bf8v*)&AsL[cur][(wm + i*16 + l15)*BK + quad*8];
      bfh[i] = *(const bf8v*)&BsH[cur][(wn + i*16 + l15)*BK + quad*8];
      bfl[i] = *(const bf8v*)&BsL[cur][(wn + i*16 + l15)*BK + quad*8];
    }
    #pragma unroll
    for (int i = 0; i < 2; i++)
      #pragma unroll
      for (int j = 0; j < 2; j++){
        acc[i][j] = __builtin_amdgcn_mfma_f32_16x16x32_bf16(afh[i], bfl[j], acc[i][j], 0, 0, 0);
        acc[i][j] = __builtin_amdgcn_mfma_f32_16x16x32_bf16(afl[i], bfh[j], acc[i][j], 0, 0, 0);
        acc[i][j] = __builtin_amdgcn_mfma_f32_16x16x32_bf16(afh[i], bfh[j], acc[i][j], 0, 0, 0);
      }
    asm volatile("s_waitcnt lgkmcnt(0)" ::: "memory");
    __builtin_amdgcn_s_barrier();
    asm volatile("" ::: "memory");
    if (t + 2 < nt) STAGE(cur, (t+2)*BK);
  }
  #pragma unroll
  for (int i = 0; i < 2; i++){
    int m0 = bm + wm + i*16 + quad*4;
    #pragma unroll
    for (int j = 0; j < 2; j++){
      int n = bn + wn + j*16 + l15;
      float bsv = bias[n];
      #pragma unroll
      for (int r = 0; r < 4; r++){
        int m = m0 + r;
        float c = acc[i][j][r] + bsv;
        if (which == 3) c = c / (1.0f + expf(-c));   // silu on gate
        out[(size_t)m*N + n] = c;
      }
    }
  }
}

__global__ void rope_kernel(float* __restrict__ q, float* __restrict__ k){
  int idx = blockIdx.x*256 + threadIdx.x;
  if (idx >= M*256) return;
  int r = idx >> 8, p = idx & 255;
  int hh = p >> 5, i = p & 31;
  int s = r % SEQ;
  float inv = powf(10000.0f, -(float)(2*i) * (1.0f/64.0f));
  float ang = (float)s * inv;
  float sn, c; sincosf(ang, &sn, &c);
  size_t base = (size_t)r*DMODEL + hh*64 + i;
  float q1 = q[base], q2 = q[base+32];
  q[base]    = q1*c - q2*sn;
  q[base+32] = q2*c + q1*sn;
  float k1 = k[base], k2 = k[base+32];
  const float sc = 0.125f;   // dh^-0.5
  k[base]    = (k1*c - k2*sn)*sc;
  k[base+32] = (k2*c + k1*sn)*sc;
}

// ---------------- retention, 3-phase parallel scan ----------------
__global__ __launch_bounds__(256) void ret_chunkkv_kernel(
    const float* __restrict__ k, const float* __restrict__ v, float* __restrict__ Ast)
{
  __shared__ __align__(16) float kT[DH][CHUNK];
  __shared__ __align__(16) float vs[CHUNK][DH];
  __shared__ float gpw[CHUNK];
  int tid = threadIdx.x;
  int c = blockIdx.x % NCHUNK;
  int bh = blockIdx.x / NCHUNK;
  int hh = bh & 7, b = bh >> 3;
  float gamma = 1.0f - exp2f(-5.0f - (float)hh);
  if (tid < CHUNK) gpw[tid] = powf(gamma, (float)(CHUNK-1-tid));
  size_t rowbase = ((size_t)(b*SEQ + c*CHUNK))*DMODEL + hh*DH;
  for (int e = tid; e < CHUNK*DH; e += 256){
    int i = e >> 6, d = e & 63;
    size_t g = rowbase + (size_t)i*DMODEL + d;
    kT[d][i] = k[g];
    vs[i][d] = v[g];
  }
  __syncthreads();
  float* A = Ast + (size_t)blockIdx.x * (DH*DH);
  for (int e = tid; e < DH*16; e += 256){
    int d = e >> 4, q4 = (e & 15) * 4;
    float4 a4 = {0,0,0,0};
    for (int j = 0; j < CHUNK; j++){
      float kj = kT[d][j] * gpw[j];
      float4 v4 = *(const float4*)&vs[j][q4];
      a4.x += kj*v4.x; a4.y += kj*v4.y; a4.z += kj*v4.z; a4.w += kj*v4.w;
    }
    *(float4*)&A[d*DH + q4] = a4;
  }
}

__global__ __launch_bounds__(256) void ret_scan_kernel(float* __restrict__ Ast)
{
  int bh = blockIdx.x, hh = bh & 7;
  float gamma = 1.0f - exp2f(-5.0f - (float)hh);
  float chdec = powf(gamma, (float)CHUNK);
  int tid = threadIdx.x;
  float4 run[4];
  #pragma unroll
  for (int t = 0; t < 4; t++) run[t] = (float4){0,0,0,0};
  size_t base = (size_t)bh * NCHUNK * (DH*DH) + (size_t)tid*16;
  for (int c = 0; c < NCHUNK; c++){
    float4* slot = (float4*)(Ast + base + (size_t)c*(DH*DH));
    float4 a[4];
    #pragma unroll
    for (int t = 0; t < 4; t++) a[t] = slot[t];
    #pragma unroll
    for (int t = 0; t < 4; t++) slot[t] = run[t];
    #pragma unroll
    for (int t = 0; t < 4; t++){
      run[t].x = run[t].x*chdec + a[t].x;
      run[t].y = run[t].y*chdec + a[t].y;
      run[t].z = run[t].z*chdec + a[t].z;
      run[t].w = run[t].w*chdec + a[t].w;
    }
  }
}

__global__ __launch_bounds__(256) void ret_out_kernel(
    const float* __restrict__ q, const float* __restrict__ k, const float* __restrict__ v,
    const float* __restrict__ Ast, float* __restrict__ ret)
{
  __shared__ __align__(16) float qs[CHUNK][DH];
  __shared__ __align__(16) float kT[DH][CHUNK];
  __shared__ __align__(16) float vs[CHUNK][DH];
  __shared__ __align__(16) float sts[DH*DH];
  __shared__ float inner[34][CHUNK];
  __shared__ float gpw[CHUNK];
  int tid = threadIdx.x;
  int c = blockIdx.x % NCHUNK;
  int bh = blockIdx.x / NCHUNK;
  int hh = bh & 7, b = bh >> 3;
  float gamma = 1.0f - exp2f(-5.0f - (float)hh);
  if (tid < CHUNK) gpw[tid] = powf(gamma, (float)tid);
  size_t rowbase = ((size_t)(b*SEQ + c*CHUNK))*DMODEL + hh*DH;
  for (int e = tid; e < CHUNK*DH; e += 256){
    int i = e >> 6, d = e & 63;
    size_t g = rowbase + (size_t)i*DMODEL + d;
    qs[i][d] = q[g];
    kT[d][i] = k[g];
    vs[i][d] = v[g];
  }
  const float* st = Ast + (size_t)blockIdx.x * (DH*DH);
  for (int e = tid*4; e < DH*DH; e += 1024)
    *(float4*)&sts[e] = *(const float4*)&st[e];
  __syncthreads();
  for (int p = 0; p < 2; p++){
    int i0 = p*34;
    for (int e = tid; e < 34*CHUNK; e += 256){
      int ii = e / CHUNK, j = e - ii*CHUNK;
      int i = i0 + ii;
      float val = 0.0f;
      if (j <= i){
        float dot = 0.0f;
        #pragma unroll 16
        for (int d = 0; d < DH; d++) dot += qs[i][d] * kT[d][j];
        val = dot * gpw[i-j];
      }
      inner[ii][j] = val;
    }
    __syncthreads();
    for (int e = tid; e < 34*16; e += 256){
      int ii = e >> 4, q4 = (e & 15) * 4;
      int i = i0 + ii;
      float4 o4 = {0,0,0,0};
      for (int j = 0; j <= i; j++){
        float w = inner[ii][j];
        float4 v4 = *(const float4*)&vs[j][q4];
        o4.x += w*v4.x; o4.y += w*v4.y; o4.z += w*v4.z; o4.w += w*v4.w;
      }
      float4 c4 = {0,0,0,0};
      #pragma unroll 8
      for (int e2 = 0; e2 < DH; e2++){
        float qv = qs[i][e2];
        float4 s4 = *(const float4*)&sts[e2*DH + q4];
        c4.x += qv*s4.x; c4.y += qv*s4.y; c4.z += qv*s4.z; c4.w += qv*s4.w;
      }
      float cd = gpw[i] * gamma;   // gamma^(i+1)
      size_t ob = rowbase + (size_t)i*DMODEL + q4;
      float4 o; o.x = o4.x + cd*c4.x; o.y = o4.y + cd*c4.y;
      o.z = o4.z + cd*c4.z; o.w = o4.w + cd*c4.w;
      *(float4*)&ret[ob] = o;
    }
    __syncthreads();
  }
}

// groupnorm (fp32 in) -> *gate -> bf16 pair out
__global__ __launch_bounds__(512) void gnorm_gate_kernel(const float* __restrict__ ret,
    const float* __restrict__ g, const float* __restrict__ gnw, const float* __restrict__ gnb,
    ushort_t* __restrict__ ohi, ushort_t* __restrict__ olo)
{
  int r = blockIdx.x, tid = threadIdx.x;   // 8 waves; wave w == head w
  size_t idx = (size_t)r*DMODEL + tid;
  float val = ret[idx];
  float s = val, s2 = val*val;
  #pragma unroll
  for (int o = 32; o; o >>= 1){ s += __shfl_xor(s, o); s2 += __shfl_xor(s2, o); }
  float mean = s * (1.0f/64.0f);
  float var  = s2 * (1.0f/64.0f) - mean*mean;
  float y = (val - mean) * rsqrtf(var + EPS);
  y = y * gnw[tid] + gnb[tid];
  y = y * g[idx];
  unsigned short hi, lo; split2(y, hi, lo);
  ohi[idx] = hi; olo[idx] = lo;
}

__global__ void outwrite_kernel(const float* __restrict__ x, float* __restrict__ out){
  int idx = blockIdx.x*256 + threadIdx.x;
  if (idx < M*DMODEL) out[idx] = x[idx];
}

extern "C" void kernel_launch(void* const* d_in, const int* in_sizes, int n_in,
                              void* d_out, int out_size, void* d_ws, size_t ws_size,
                              hipStream_t stream)
{
  (void)in_sizes; (void)n_in; (void)out_size; (void)ws_size;
  const int*   tokens = (const int*)d_in[0];
  const float* emb  = (const float*)d_in[1];
  const float* Wq = (const float*)d_in[2];  const float* bq = (const float*)d_in[3];
  const float* Wk = (const float*)d_in[4];  const float* bk = (const float*)d_in[5];
  const float* Wv = (const float*)d_in[6];  const float* bv = (const float*)d_in[7];
  const float* Wg = (const float*)d_in[8];  const float* bg = (const float*)d_in[9];
  const float* Wo = (const float*)d_in[10]; const float* bo = (const float*)d_in[11];
  const float* gnw = (const float*)d_in[12]; const float* gnb = (const float*)d_in[13];
  const float* ln1w = (const float*)d_in[14]; const float* ln1b = (const float*)d_in[15];
  const float* ln2w = (const float*)d_in[16]; const float* ln2b = (const float*)d_in[17];
  const float* w1 = (const float*)d_in[18]; const float* b1 = (const float*)d_in[19];
  const float* w2 = (const float*)d_in[20]; const float* b2 = (const float*)d_in[21];

  const size_t MD = (size_t)M*DMODEL;
  float* xf = (float*)d_ws;     // fp32 residual [M,512]
  float* qf = xf + MD;          // fp32 q
  float* kf = qf + MD;          // fp32 k
  float* vf = kf + MD;          // fp32 v
  float* gf = vf + MD;          // fp32 gate (silu'd)
  float* rf = gf + MD;          // fp32 retention out / split-weight scratch
  ushort_t* h_hi = (ushort_t*)(rf + MD);  // bf16 LN-out pair [M,512]
  ushort_t* h_lo = h_hi + MD;
  // A/state buffer [768,4096] fp32 (12.58 MB) time-shares the h pair (13.37 MB)
  float* Ast = (float*)h_hi;
  ushort_t* rg_hi = h_hi;
  ushort_t* rg_lo = h_lo;
  ushort_t* ff_hi = (ushort_t*)qf;
  ushort_t* ff_lo = (ushort_t*)vf;
  ushort_t* wsp = (ushort_t*)rf;
  // total footprint unchanged: 6*MD*4 + 2*MD*2 = 93.6 MB (< proven 95.7 MB)

  embed_kernel<<<(M*DMODEL)/256, 256, 0, stream>>>(tokens, emb, xf);

  dim3 gqkvg(32, M/64);           // fused QKVG, TBN=64: (32,102)=3264 blocks
  dim3 g512(DMODEL/64, M/64);     // Wo: (8,102)=816 blocks
  dim3 gff(FFDIM/64, M/64);       // w1, TBN=64: (32,102)=3264 blocks
  dim3 gw2(DMODEL/64, M/64, 4);   // w2 split-K=4: (8,102,4)=3264 blocks
  dim3 gsplit4(16, 16, 4);        // qkvg weight split
  for (int l = 0; l < NLAYER; l++){
    const size_t wO = (size_t)l*DMODEL*DMODEL;
    const size_t bO = (size_t)l*DMODEL;
    const size_t w1O = (size_t)l*DMODEL*FFDIM;
    const size_t b1O = (size_t)l*FFDIM;
    wsplit_qkvg_kernel<<<gsplit4, 256, 0, stream>>>(Wq + wO, Wk + wO, Wv + wO, Wg + wO, wsp);
    ln_kernel<<<M, 256, 0, stream>>>(xf, ln1w + bO, ln1b + bO, h_hi, h_lo);
    gemm_qkvg_kernel<<<gqkvg, 256, 0, stream>>>(h_hi, h_lo, wsp,
        bq + bO, bk + bO, bv + bO, bg + bO,
        qf, kf, vf, gf);
    rope_kernel<<<M, 256, 0, stream>>>(qf, kf);
    ret_chunkkv_kernel<<<BATCH*H*NCHUNK, 256, 0, stream>>>(kf, vf, Ast);
    ret_scan_kernel<<<BATCH*H, 256, 0, stream>>>(Ast);
    ret_out_kernel<<<BATCH*H*NCHUNK, 256, 0, stream>>>(qf, kf, vf, Ast, rf);
    gnorm_gate_kernel<<<M, 512, 0, stream>>>(rf, gf, gnw + bO, gnb + bO, rg_hi, rg_lo);
    wsplit_ffo_kernel<<<2304, 256, 0, stream>>>(Wo + wO, w1 + w1O, w2 + w1O, wsp);
    gemm_ps_kernel<64><<<g512, 256, 0, stream>>>(rg_hi, rg_lo,
        wsp + WO_HI, wsp + WO_LO, bo + bO, xf, xf, nullptr, nullptr, DMODEL, DMODEL, 2);
    ln_kernel<<<M, 256, 0, stream>>>(xf, ln2w + bO, ln2b + bO, h_hi, h_lo);
    gemm_ps_kernel<64><<<gff, 256, 0, stream>>>(h_hi, h_lo,
        wsp + W1_HI, wsp + W1_LO, b1 + b1O, nullptr, nullptr, ff_hi, ff_lo, FFDIM, DMODEL, 1);
    gemm_ps_kernel<64><<<gw2, 256, 0, stream>>>(ff_hi, ff_lo,
        wsp + W2_HI, wsp + W2_LO, b2 + bO, nullptr, xf, nullptr, nullptr, DMODEL, FFDIM, 3);
  }
  outwrite_kernel<<<(M*DMODEL)/256, 256, 0, stream>>>(xf, (float*)d_out);
}